// Round 10
// baseline (233.256 us; speedup 1.0000x reference)
//
#include <hip/hip_runtime.h>
#include <math.h>

constexpr int kB  = 16;
constexpr int kS  = 256;
constexpr int kD  = 1024;
constexpr int kH  = 16;
constexpr float kScale = 0.125f;  // 1/sqrt(64)

using bf16x8  = __attribute__((ext_vector_type(8))) short;
using floatx4 = __attribute__((ext_vector_type(4))) float;
typedef unsigned short u16;

__device__ __forceinline__ u16 f2bf(float x) {
  union { float f; unsigned u; } v; v.f = x;
  unsigned r = v.u + 0x7fffu + ((v.u >> 16) & 1u);
  return (u16)(r >> 16);
}
__device__ __forceinline__ float bf2f(u16 h) {
  union { unsigned u; float f; } v; v.u = ((unsigned)h) << 16;
  return v.f;
}

#define MFMA16(a, b, c) __builtin_amdgcn_mfma_f32_16x16x32_bf16((a), (b), (c), 0, 0, 0)
#define GLL16(gp, lp)                                                        \
  __builtin_amdgcn_global_load_lds(                                          \
      (const __attribute__((address_space(1))) unsigned int*)(gp),           \
      (__attribute__((address_space(3))) unsigned int*)(lp), 16, 0, 0)

// ---------------- pack + table: xA=[x;table], W3=[Wq;Wv;Wk], Wo, b3 ----------
__global__ __launch_bounds__(256) void pack_k(
    const float* __restrict__ x, const float* __restrict__ Wq,
    const float* __restrict__ Wk, const float* __restrict__ Wv,
    const float* __restrict__ Wo,
    const float* __restrict__ bq, const float* __restrict__ bk,
    const float* __restrict__ bv,
    u16* __restrict__ xA, u16* __restrict__ W3b, u16* __restrict__ Wob,
    float* __restrict__ b3) {
  size_t i = ((size_t)blockIdx.x * 256 + threadIdx.x) * 4;
  const size_t NX = (size_t)4194304, NW = (size_t)1048576;
  const size_t BEND = NX + 4 * NW + 3072;
  const float* src;
  u16* dst;
  size_t o;
  if (i < NX) {
    src = x; dst = xA; o = i;
  } else if (i < NX + 3 * NW) {
    size_t j = i - NX;
    int sel = (int)(j >> 20);
    o = j & (NW - 1);
    src = sel == 0 ? Wq : sel == 1 ? Wv : Wk;
    dst = W3b + (size_t)sel * NW;
  } else if (i < NX + 4 * NW) {
    o = i - NX - 3 * NW;
    src = Wo; dst = Wob;
  } else if (i < BEND) {
    size_t j = i - NX - 4 * NW;
    int sel = (int)(j >> 10);
    o = j & 1023;
    src = sel == 0 ? bq : sel == 1 ? bv : bk;
    *reinterpret_cast<float4*>(b3 + j) = *reinterpret_cast<const float4*>(src + o);
    return;
  } else if (i < BEND + 262144) {
    // sinusoid table rows p in [0,256), pos = p-255 -> xA rows 4096..4351
    size_t j = i - BEND;
    int p = (int)(j >> 10);
    int ibase = (int)(j & 1023);
    ushort4 r;
    u16* rr = (u16*)&r;
#pragma unroll
    for (int c = 0; c < 4; ++c) {
      int idx = ibase + c;
      float ex = (float)(2 * (idx / 2)) * (1.0f / 1024.0f);
      float scale = exp2f(ex * -13.287712379549449f);  // 10000^-ex
      float angle = (float)(p - 255) * scale;
      rr[c] = f2bf((idx & 1) ? cosf(angle) : sinf(angle));
    }
    *reinterpret_cast<ushort4*>(xA + NX + j) = r;
    return;
  } else {
    return;
  }
  float4 v = *reinterpret_cast<const float4*>(src + o);
  ushort4 r;
  r.x = f2bf(v.x); r.y = f2bf(v.y); r.z = f2bf(v.z); r.w = f2bf(v.w);
  *reinterpret_cast<ushort4*>(dst + o) = r;
}

// ---------------- rank-16 fold of Wr with u/v: W3b rows 3072..3103, b3 tail ------
__global__ __launch_bounds__(256) void uv_fold_k(
    const float* __restrict__ Wr, const float* __restrict__ br,
    const float* __restrict__ ub, const float* __restrict__ vb,
    u16* __restrict__ W3b, float* __restrict__ b3) {
  int gid = blockIdx.x * 256 + threadIdx.x;  // 32768
  int j = gid >> 10, c = gid & 1023;
  int h = j & 15;
  const float* bvec = (j < 16 ? ub : vb) + h * 64;
  const float* wcol = Wr + (size_t)(h * 64) * 1024 + c;
  float a = 0.f;
#pragma unroll
  for (int d = 0; d < 64; ++d) a += bvec[d] * wcol[(size_t)d * 1024];
  W3b[(size_t)(3072 + j) * 1024 + c] = f2bf(a);
  if (gid < 128) {
    float s = 0.f;
    if (gid < 32) {
      const float* bv2 = (gid < 16 ? ub : vb) + (gid & 15) * 64;
      const float* brp = br + (gid & 15) * 64;
      for (int d = 0; d < 64; ++d) s += bv2[d] * brp[d];
    }
    b3[3072 + gid] = s;
  }
}

// ---------------- bf16 MFMA GEMM: C = A @ W^T + bias ----------------
// 128x128 tile, 256 threads (2x2 waves), BK=64, GLL16 staging, XOR-swizzled LDS.
// SWIZ=0: plain 2D grid (blockIdx.x=bn tile, blockIdx.y=bm tile). [r9 lesson:
//   the XCD-slab ordering on the 850-block proj GEMM *hurt* (72->113us) — L2
//   overcommit converted streaming hits into LLC round-trips; plain 2D is best.]
// SWIZ=1: XCD-slab 1D grid (kept for the 256-block out-GEMM where it won big).
// OUT_MODE 0: fp32 flat row-major.
// OUT_MODE 2: head-major multi-tensor epilogue; rows >= 4096 are table rows;
//   cols 3072..3087 -> utb fp32, 3088..3103 -> dtb fp32, >=3104 discarded.
template <int OUT_MODE, int SWIZ>
__global__ __launch_bounds__(256) void gemm_k(
    const u16* __restrict__ A, const u16* __restrict__ W,
    const float* __restrict__ bias, void* __restrict__ Cv,
    int M, int N, int K, float* __restrict__ utb, float* __restrict__ dtb,
    int mTiles, int nTiles) {
  int bm, bn;
  if (SWIZ == 0) {
    bm = blockIdx.y * 128;
    bn = blockIdx.x * 128;
  } else {
    const int xcd = blockIdx.x & 7;
    const int li  = blockIdx.x >> 3;
    const int r0   = (xcd * mTiles) >> 3;
    const int rcnt = (((xcd + 1) * mTiles) >> 3) - r0;
    if (li >= rcnt * nTiles) return;
    bm = (r0 + li % rcnt) * 128;
    bn = (li / rcnt) * 128;
  }

  __shared__ u16 Alds[128 * 64];
  __shared__ u16 Blds[128 * 64];
  const int t = threadIdx.x, w = t >> 6, l = t & 63;
  const int l15 = l & 15, quad = l >> 4;
  const int wm = w >> 1, wn = w & 1;
  const int lrow8 = l >> 3;
  const int kslot = l & 7;

  floatx4 acc[4][4] = {};

  for (int k0 = 0; k0 < K; k0 += 64) {
#pragma unroll
    for (int sg = 0; sg < 4; ++sg) {
      int mrow = sg * 32 + w * 8 + lrow8;
      int gk = (kslot ^ (mrow & 7)) << 3;
      GLL16(A + (size_t)(bm + mrow) * K + k0 + gk, Alds + (sg * 32 + w * 8) * 64);
      GLL16(W + (size_t)(bn + mrow) * K + k0 + gk, Blds + (sg * 32 + w * 8) * 64);
    }
    __syncthreads();
#pragma unroll
    for (int c = 0; c < 2; ++c) {
      bf16x8 af[4], bf[4];
#pragma unroll
      for (int mi = 0; mi < 4; ++mi) {
        int am = wm * 64 + mi * 16 + l15;
        af[mi] = *(const bf16x8*)(Alds + am * 64 + (((c * 4 + quad) ^ (am & 7)) << 3));
      }
#pragma unroll
      for (int ni = 0; ni < 4; ++ni) {
        int an = wn * 64 + ni * 16 + l15;
        bf[ni] = *(const bf16x8*)(Blds + an * 64 + (((c * 4 + quad) ^ (an & 7)) << 3));
      }
#pragma unroll
      for (int mi = 0; mi < 4; ++mi)
#pragma unroll
        for (int ni = 0; ni < 4; ++ni)
          acc[mi][ni] = MFMA16(af[mi], bf[ni], acc[mi][ni]);
    }
    __syncthreads();
  }

#pragma unroll
  for (int ni = 0; ni < 4; ++ni) {
    int col = bn + wn * 64 + ni * 16 + l15;
    float bv = bias[col];
#pragma unroll
    for (int mi = 0; mi < 4; ++mi) {
      int mrow = bm + wm * 64 + mi * 16 + quad * 4;
#pragma unroll
      for (int r = 0; r < 4; ++r) {
        float v = acc[mi][ni][r] + bv;
        int row = mrow + r;
        if (OUT_MODE == 0) {
          ((float*)Cv)[(size_t)row * N + col] = v;
        } else {
          if (col < 3072) {
            int matsel = col >> 10;        // 0=Q,1=V,2=K
            int hh = (col >> 6) & 15, dd = col & 63;
            if (row < 4096) {
              int bb = row >> 8, ss = row & 255;
              ((u16*)Cv)[(size_t)matsel * 4194304 +
                         ((size_t)(((bb << 4) + hh) << 8) + ss) * 64 + dd] = f2bf(v);
            } else if (matsel == 2) {      // table @ Wk^T -> RPKh
              int pp = row - 4096;
              ((u16*)Cv)[(size_t)3 * 4194304 +
                         ((size_t)((hh << 8) + pp)) * 64 + dd] = f2bf(v);
            }
          } else if (col < 3088) {
            if (row < 4096)
              utb[((row >> 8) * 16 + (col - 3072)) * 256 + (row & 255)] = v;
          } else if (col < 3104) {
            if (row >= 4096)
              dtb[(col - 3088) * 256 + (row - 4096)] = v;
          }
        }
      }
    }
  }
}

// ---------------- fused attention: one block per (b,h), K/V in LDS ----------------
__global__ __launch_bounds__(512, 2) void attn_k(
    const u16* __restrict__ Qh, const u16* __restrict__ Kh,
    const u16* __restrict__ Vh, const u16* __restrict__ RPKh,
    const float* __restrict__ ut, const float* __restrict__ dt,
    u16* __restrict__ vw) {
  __shared__ u16 Klds[256 * 64];     // 32 KB, XOR-swizzled rows
  __shared__ u16 Vt[64][280];        // 35 KB, V transposed
  __shared__ float Sc[32][257];      // scores by z
  __shared__ float Sc2[32][257];     // rel scores by p
  __shared__ float Ut[256], Dt[256], Rinv[32];

  const int bh = blockIdx.x;         // b*16 + h
  const int h = bh & 15;
  const int b = bh >> 4;
  const size_t bh256 = (size_t)bh << 8;

  const int t = threadIdx.x, w = t >> 6, l = t & 63;
  const int l15 = l & 15, quad = l >> 4;

  // ---- staging: K (GLL16), V^T (LDS transpose), Ut, Dt ----
  {
    const int lrow8 = l >> 3, kslot = l & 7;
#pragma unroll
    for (int i = 0; i < 4; ++i) {
      int row = w * 32 + i * 8 + lrow8;
      int gk = (kslot ^ (row & 7)) << 3;
      GLL16(Kh + (bh256 + row) * 64 + gk, Klds + (w * 32 + i * 8) * 64);
    }
  }
  {
    int z = t & 255, dh = t >> 8;    // dh: 0..1 (wave-uniform)
    const u16* gp = Vh + (bh256 + z) * 64 + dh * 32;
    ushort4 vv[8];
#pragma unroll
    for (int i = 0; i < 8; ++i) vv[i] = *(const ushort4*)(gp + i * 4);
#pragma unroll
    for (int i = 0; i < 8; ++i) {
      Vt[dh * 32 + i * 4 + 0][z] = vv[i].x;
      Vt[dh * 32 + i * 4 + 1][z] = vv[i].y;
      Vt[dh * 32 + i * 4 + 2][z] = vv[i].z;
      Vt[dh * 32 + i * 4 + 3][z] = vv[i].w;
    }
  }
  if (t < 256) Ut[t] = ut[bh256 + t];
  else         Dt[t - 256] = dt[((size_t)h << 8) + (t - 256)];
  __syncthreads();

  // ---- loop over 8 s-tiles of 32 rows ----
  for (int st = 0; st < 8; ++st) {
    const int s0 = st * 32;

    bf16x8 qa[2][2];
#pragma unroll
    for (int rt = 0; rt < 2; ++rt) {
      const u16* qp = Qh + (bh256 + s0 + rt * 16 + l15) * 64 + quad * 8;
      qa[rt][0] = *(const bf16x8*)qp;
      qa[rt][1] = *(const bf16x8*)(qp + 32);
    }

    // merged QK (-> Sc) + QR (-> Sc2); tasks round-robin over 8 waves
    {
      int cnt = 0;
#pragma unroll
      for (int rt = 0; rt < 2; ++rt) {
        const int rB = s0 + rt * 16;
        const int nzt = 2 * st + rt + 1;
        for (int zt = 0; zt < nzt; ++zt, ++cnt) {
          if ((cnt & 7) != w) continue;  // wave-uniform
          const int zr = (zt << 4) + l15;
          const u16* krow = Klds + zr * 64;
          bf16x8 kb0 = *(const bf16x8*)(krow + ((quad ^ (zr & 7)) << 3));
          bf16x8 kb1 = *(const bf16x8*)(krow + (((quad + 4) ^ (zr & 7)) << 3));
          floatx4 acc = {};
          acc = MFMA16(qa[rt][0], kb0, acc);
          acc = MFMA16(qa[rt][1], kb1, acc);
          float u = Ut[zr];
#pragma unroll
          for (int r = 0; r < 4; ++r)
            Sc[rt * 16 + quad * 4 + r][zr] = acc[r] + u;
        }
        for (int j = 0; j < nzt; ++j, ++cnt) {
          if ((cnt & 7) != w) continue;
          const int pr = 240 - rB + (j << 4) + l15;
          const u16* rp = RPKh + ((size_t)(h << 8) + pr) * 64 + quad * 8;
          bf16x8 rb0 = *(const bf16x8*)rp;
          bf16x8 rb1 = *(const bf16x8*)(rp + 32);
          floatx4 acc = {};
          acc = MFMA16(qa[rt][0], rb0, acc);
          acc = MFMA16(qa[rt][1], rb1, acc);
          float dv = Dt[pr];
#pragma unroll
          for (int r = 0; r < 4; ++r)
            Sc2[rt * 16 + quad * 4 + r][pr] = acc[r] + dv;
        }
      }
    }
    __syncthreads();

    // softmax: 4 rows/wave, 16 lanes/row; P -> Sc
    {
      const int row = w * 4 + (l >> 4);
      const int c16 = l & 15;
      const int s = s0 + row;
      const int zfill = 32 * (st + 1);
      float m = -1e30f;
      for (int z = c16; z <= s; z += 16)
        m = fmaxf(m, Sc[row][z] + Sc2[row][z - s + 255]);
      m = fmaxf(m, __shfl_xor(m, 1));
      m = fmaxf(m, __shfl_xor(m, 2));
      m = fmaxf(m, __shfl_xor(m, 4));
      m = fmaxf(m, __shfl_xor(m, 8));
      m *= kScale;
      float sum = 0.f;
      for (int z = c16; z < zfill; z += 16) {
        float e = 0.f;
        if (z <= s) {
          e = __expf((Sc[row][z] + Sc2[row][z - s + 255]) * kScale - m);
          sum += e;
        }
        Sc[row][z] = e;
      }
      sum += __shfl_xor(sum, 1);
      sum += __shfl_xor(sum, 2);
      sum += __shfl_xor(sum, 4);
      sum += __shfl_xor(sum, 8);
      if (c16 == 0) Rinv[row] = 1.f / sum;
    }
    __syncthreads();

    // PV: wave = (strip = w>>2, nt = w&3); V from LDS
    {
      const int strip = w >> 2, nt = w & 3;
      const int sB = s0 + strip * 16;
      floatx4 oacc = {};
      for (int kc = 0; kc <= st; ++kc) {
        const float* prow = &Sc[strip * 16 + l15][kc * 32 + quad * 8];
        bf16x8 pa;
        pa[0] = (short)f2bf(prow[0]); pa[1] = (short)f2bf(prow[1]);
        pa[2] = (short)f2bf(prow[2]); pa[3] = (short)f2bf(prow[3]);
        pa[4] = (short)f2bf(prow[4]); pa[5] = (short)f2bf(prow[5]);
        pa[6] = (short)f2bf(prow[6]); pa[7] = (short)f2bf(prow[7]);
        const u16* vp = &Vt[nt * 16 + l15][kc * 32 + quad * 8];
        bf16x8 vbf = *(const bf16x8*)vp;
        oacc = MFMA16(pa, vbf, oacc);
      }
#pragma unroll
      for (int r = 0; r < 4; ++r) {
        float ivr = Rinv[strip * 16 + quad * 4 + r];
        int srow = sB + quad * 4 + r;
        vw[(size_t)(b * 256 + srow) * 1024 + h * 64 + nt * 16 + l15] =
            f2bf(oacc[r] * ivr);
      }
    }
    __syncthreads();
  }
}

extern "C" void kernel_launch(void* const* d_in, const int* in_sizes, int n_in,
                              void* d_out, int out_size, void* d_ws, size_t ws_size,
                              hipStream_t stream) {
  const float* x  = (const float*)d_in[0];
  const float* Wq = (const float*)d_in[1];
  const float* bq = (const float*)d_in[2];
  const float* Wk = (const float*)d_in[3];
  const float* bk = (const float*)d_in[4];
  const float* Wv = (const float*)d_in[5];
  const float* bv = (const float*)d_in[6];
  const float* Wr = (const float*)d_in[7];
  const float* br = (const float*)d_in[8];
  const float* ub = (const float*)d_in[9];
  const float* vb = (const float*)d_in[10];
  const float* Wo = (const float*)d_in[11];
  const float* bo = (const float*)d_in[12];
  float* out = (float*)d_out;

  char* base = (char*)d_ws;
  size_t off = 0;
  auto alloc = [&](size_t bytes) {
    void* p = base + off;
    off += (bytes + 255) & ~(size_t)255;
    return p;
  };

  const size_t MAT = (size_t)4194304;  // 4096*1024
  u16*   xA    = (u16*)alloc((size_t)4352 * 1024 * 2);       // [x ; table]
  u16*   W3b   = (u16*)alloc((size_t)3200 * 1024 * 2);       // [Wq;Wv;Wk;UV;pad]
  u16*   Wob   = (u16*)alloc((size_t)1024 * 1024 * 2);
  float* b3    = (float*)alloc((size_t)3200 * 4);            // [bq;bv;bk;ub.br;vb.br;0]
  u16*   Ph    = (u16*)alloc((3 * MAT + 262144) * 2);        // Qh,Vh,Kh,RPKh
  float* utb   = (float*)alloc((size_t)65536 * 4);
  float* dtb   = (float*)alloc((size_t)4096 * 4);
  u16*   vwb   = (u16*)alloc((size_t)4096 * 1024 * 2);

  u16* Qh   = Ph;
  u16* Vh   = Ph + MAT;
  u16* Kh   = Ph + 2 * MAT;
  u16* RPKh = Ph + 3 * MAT;

  // pack + table
  pack_k<<<dim3(8451), dim3(256), 0, stream>>>(x, Wq, Wk, Wv, Wo, bq, bk, bv,
                                               xA, W3b, Wob, b3);
  // rank-16 fold of Wr with u/v biases -> W3b rows 3072.., b3 tail
  uv_fold_k<<<dim3(128), dim3(256), 0, stream>>>(Wr, br, ub, vb, W3b, b3);

  // fused Q|V|K + relpos-K + ut/dt projections: 4352 x 3200 x 1024, plain 2D grid
  gemm_k<2, 0><<<dim3(25, 34), dim3(256), 0, stream>>>(xA, W3b, b3, Ph,
                                                       4352, 3200, 1024, utb, dtb,
                                                       34, 25);

  // fused attention: one block per (b,h)
  attn_k<<<dim3(256), dim3(512), 0, stream>>>(Qh, Kh, Vh, RPKh, utb, dtb, vwb);

  // output projection: 4096 x 1024 x 1024, fp32 out; XCD-slab grid (won in r9)
  gemm_k<0, 1><<<dim3(256), dim3(256), 0, stream>>>(vwb, Wob, bo, out,
                                                    4096, 1024, 1024, nullptr, nullptr,
                                                    32, 8);
}